// Round 6
// baseline (55.163 us; speedup 1.0000x reference)
//
#include <hip/hip_runtime.h>
#include <hip/hip_bf16.h>
#include <math.h>

// Gaussian upsampling, round 6: cooperative w-tile (no redundant exp) + PE table.
//   prepass1: enc (B,S,D) f32 -> encT (B,D,S) bf16 in d_ws        (validated)
//   prepass2: pe[T,D] f32 table in d_ws+4MB (sinusoidal PE)
//   main    : grid = B x (T/32), 256-thread blocks, 2 barriers:
//     - per-wave shfl scan -> s_c / s_nir (benign identical-value race)
//     - exp phase: wave wid computes k-slice [wid*64,+64) of shared A-tile
//       [32][256] bf16, XOR-swizzled ((r&15)<<4); w2 partials -> s_part
//     - barrier #1 ; wave0 threads build s_winv[32]
//     - k-loop: A from LDS (ds_read_b128, swizzled), B prefetched from L2-resident
//       encT, 8 MFMA per step, zero barriers
//     - barrier #2 ; epilogue reuses A-tile as per-wave staging -> LDS transpose,
//       *1/w2 + pe-table add, coalesced dwordx4 stores

typedef short  bf16x8 __attribute__((ext_vector_type(8)));
typedef float  f32x4  __attribute__((ext_vector_type(4)));
typedef unsigned short u16x8 __attribute__((ext_vector_type(8)));

#define S_FIX 256
#define D_FIX 256
#define BM 32          // t-rows per block (shared by all 4 waves)
#define BN 64          // d-cols per wave
#define STG 68         // staging stride in floats (272 B); per-wave 16*68*4 = 4352 B

static __device__ __forceinline__ unsigned short f2bf(float f) {
    union { float f; unsigned u; } v; v.f = f;
    unsigned r = v.u + 0x7FFFu + ((v.u >> 16) & 1u);   // RNE
    return (unsigned short)(r >> 16);
}

// pack two f32 -> one u32 of 2x bf16 (RNE); compiler emits v_cvt_pk_bf16_f32
static __device__ __forceinline__ unsigned pack_bf2(float lo, float hi) {
    float2 v; v.x = lo; v.y = hi;
    union { __hip_bfloat162 h; unsigned u; } c;
    c.h = __float22bfloat162_rn(v);
    return c.u;
}

// ---------------- prepass 1: enc (B,S,D) f32 -> encT (B,D,S) bf16 ----------------
__global__ __launch_bounds__(256) void transpose_enc_bf16(
    const float* __restrict__ enc, unsigned short* __restrict__ encT)
{
    const int g  = blockIdx.x * 256 + threadIdx.x;
    const int d  = g & 255;
    const int sc = (g >> 8) & 31;
    const int b  = g >> 13;
    const int s0 = sc * 8;
    const float* p = enc + ((size_t)b << 16) + (size_t)s0 * D_FIX + d;
    u16x8 v;
    #pragma unroll
    for (int j = 0; j < 8; ++j) v[j] = f2bf(p[(size_t)j * D_FIX]);
    *(u16x8*)(encT + ((size_t)b << 16) + (size_t)d * S_FIX + s0) = v;
}

// ---------------- prepass 2: pe[T,D] table ----------------
__global__ __launch_bounds__(256) void pe_table(float* __restrict__ pe)
{
    const int idx = blockIdx.x * 256 + threadIdx.x;   // T*64 threads
    const int q   = idx & 63;                          // d-quad
    const int t   = idx >> 6;
    const float kf = -logf(10000.0f) / (float)D_FIX;
    const float f0 = __expf(kf * (float)(4 * q));
    const float f2 = __expf(kf * (float)(4 * q + 2));
    float s0, c0, s2, c2;
    __sincosf((float)t * f0, &s0, &c0);
    __sincosf((float)t * f2, &s2, &c2);
    f32x4 v; v[0] = s0; v[1] = c0; v[2] = s2; v[3] = c2;
    *(f32x4*)(pe + (size_t)t * D_FIX + 4 * q) = v;
}

// ---------------- main ----------------
__global__ __launch_bounds__(256, 4) void gauss_up_mfma(
    const float* __restrict__ dur,            // (B,S)
    const float* __restrict__ rng,            // (B,S,1)
    const unsigned short* __restrict__ encT,  // (B,D,S) bf16
    const float* __restrict__ pe,             // (T,D)
    float* __restrict__ out,                  // (B,T,D)
    int T)
{
    __shared__ float s_c[S_FIX];
    __shared__ float s_nir[S_FIX];            // -1/r^2
    __shared__ float s_winv[BM];
    // union: k-phase = A-tile [32 rows][512 B] (16 KB) + s_part[8][32] (1 KB)
    //        epilogue = 4 x per-wave staging [16][STG] f32 (4 x 4352 B)
    __shared__ __align__(16) char s_uni[17408];

    const int tid  = threadIdx.x;
    const int lane = tid & 63;
    const int wid  = tid >> 6;
    const int l15  = lane & 15;
    const int lg   = lane >> 4;
    const int ntiles = T / BM;
    const int b    = blockIdx.x / ntiles;
    const int t0   = (blockIdx.x % ntiles) * BM;
    const int d0   = wid * BN;

    // ---- per-wave scan; every wave writes all 256 entries (identical values) ----
    {
        f32x4 dv = *(const f32x4*)(dur + b * S_FIX + 4 * lane);
        f32x4 rg = *(const f32x4*)(rng + b * S_FIX + 4 * lane);
        float q0 = dv[0];
        float q1 = q0 + dv[1];
        float q2 = q1 + dv[2];
        float q3 = q2 + dv[3];
        float tot = q3;
        #pragma unroll
        for (int off = 1; off < 64; off <<= 1) {
            float n = __shfl_up(tot, off, 64);
            if (lane >= off) tot += n;
        }
        float excl = __shfl_up(tot, 1, 64);
        if (lane == 0) excl = 0.0f;
        f32x4 c4, n4;
        c4[0] = excl + q0 - 0.5f * dv[0];
        c4[1] = excl + q1 - 0.5f * dv[1];
        c4[2] = excl + q2 - 0.5f * dv[2];
        c4[3] = excl + q3 - 0.5f * dv[3];
        #pragma unroll
        for (int i = 0; i < 4; ++i) n4[i] = -1.0f / (rg[i] * rg[i]);
        *(f32x4*)(s_c   + 4 * lane) = c4;
        *(f32x4*)(s_nir + 4 * lane) = n4;
    }
    asm volatile("s_waitcnt lgkmcnt(0)" ::: "memory");  // own writes visible

    // ---- exp phase: wave wid computes k-slice [wid*64, wid*64+64) ----
    // thread = (row r, k-chunk kc): 32 exps; A-tile write swizzle ((r&15)<<4)
    {
        const int r     = lane & 31;
        const int kc    = lane >> 5;
        const int kbase = wid * 64 + kc * 32;
        const float tt  = (float)(t0 + r);
        const int  swz  = (r & 15) << 4;
        char* abase = s_uni + r * 512;
        float ps = 0.0f;
        #pragma unroll
        for (int c8 = 0; c8 < 4; ++c8) {               // 8 k per chunk
            const int kk = kbase + c8 * 8;
            f32x4 cA = *(const f32x4*)(s_c   + kk);
            f32x4 cB = *(const f32x4*)(s_c   + kk + 4);
            f32x4 nA = *(const f32x4*)(s_nir + kk);
            f32x4 nB = *(const f32x4*)(s_nir + kk + 4);
            #pragma unroll
            for (int j = 0; j < 4; ++j) {              // k pair (2j, 2j+1)
                const float c0_ = (j < 2) ? cA[(2 * j) & 3]     : cB[(2 * j) & 3];
                const float c1_ = (j < 2) ? cA[(2 * j + 1) & 3] : cB[(2 * j + 1) & 3];
                const float n0_ = (j < 2) ? nA[(2 * j) & 3]     : nB[(2 * j) & 3];
                const float n1_ = (j < 2) ? nA[(2 * j + 1) & 3] : nB[(2 * j + 1) & 3];
                float e0 = tt - c0_, e1 = tt - c1_;
                unsigned p = pack_bf2(__expf(n0_ * e0 * e0), __expf(n1_ * e1 * e1));
                *(unsigned*)(abase + ((2 * (kk + 2 * j)) ^ swz)) = p;
                ps += __uint_as_float(p << 16) + __uint_as_float(p & 0xFFFF0000u);
            }
        }
        float* s_part = (float*)(s_uni + 16384);
        s_part[(wid * 2 + kc) * 32 + r] = ps;
    }
    __syncthreads();   // barrier #1: A-tile + partials complete

    // ---- wave 0 builds s_winv (others proceed straight to k-loop) ----
    if (tid < BM) {
        const float* s_part = (const float*)(s_uni + 16384);
        float w2 = 1e-20f;
        #pragma unroll
        for (int sl = 0; sl < 8; ++sl) w2 += s_part[sl * 32 + tid];
        s_winv[tid] = 1.0f / w2;
    }

    // ---- k-loop: A from LDS, prefetched B from global, 8 MFMA / step ----
    f32x4 acc[2][4];
    #pragma unroll
    for (int m = 0; m < 2; ++m)
        #pragma unroll
        for (int n = 0; n < 4; ++n) acc[m][n] = (f32x4){0.f, 0.f, 0.f, 0.f};

    const unsigned short* eb =
        encT + ((size_t)b << 16) + (size_t)(d0 + l15) * S_FIX + lg * 8;
    const char* ab0 = s_uni + (size_t)l15 * 512;         // m=0: row l15
    const char* ab1 = s_uni + (size_t)(16 + l15) * 512;  // m=1: row 16+l15
    const int aswz = l15 << 4;   // (r&15)<<4 is identical for r and r+16

    bf16x8 bcur[4];
    #pragma unroll
    for (int n = 0; n < 4; ++n)
        bcur[n] = *(const bf16x8*)(eb + (size_t)n * 16 * S_FIX);

    #pragma unroll 2
    for (int k0 = 0; k0 < S_FIX; k0 += 32) {
        const int kn = (k0 + 32 < S_FIX) ? k0 + 32 : 0;
        bf16x8 bnext[4];
        #pragma unroll
        for (int n = 0; n < 4; ++n)
            bnext[n] = *(const bf16x8*)(eb + (size_t)n * 16 * S_FIX + kn);

        const int koff = (2 * (k0 + lg * 8)) ^ aswz;
        bf16x8 a0 = *(const bf16x8*)(ab0 + koff);
        bf16x8 a1 = *(const bf16x8*)(ab1 + koff);

        #pragma unroll
        for (int n = 0; n < 4; ++n) {
            acc[0][n] = __builtin_amdgcn_mfma_f32_16x16x32_bf16(a0, bcur[n], acc[0][n], 0, 0, 0);
            acc[1][n] = __builtin_amdgcn_mfma_f32_16x16x32_bf16(a1, bcur[n], acc[1][n], 0, 0, 0);
        }
        #pragma unroll
        for (int n = 0; n < 4; ++n) bcur[n] = bnext[n];
    }

    __syncthreads();   // barrier #2: all A reads done; s_winv published

    // ---- epilogue: per-wave staging in (reused) A-tile region ----
    float* stg = (float*)(s_uni + wid * (16 * STG * 4));
    const float* peb = pe + (size_t)t0 * D_FIX + d0 + 4 * l15;
    float* ob = out + (size_t)b * T * D_FIX + (size_t)t0 * D_FIX + d0 + 4 * l15;

    #pragma unroll
    for (int m = 0; m < 2; ++m) {
        if (m)  // wave-local WAR fence on private staging region
            asm volatile("s_waitcnt lgkmcnt(0)" ::: "memory");
        #pragma unroll
        for (int n = 0; n < 4; ++n)
            #pragma unroll
            for (int r = 0; r < 4; ++r)
                stg[(lg * 4 + r) * STG + n * 16 + l15] = acc[m][n][r];
        asm volatile("s_waitcnt lgkmcnt(0)" ::: "memory");
        #pragma unroll
        for (int i = 0; i < 4; ++i) {
            const int rr = 4 * i + lg;                    // row-local 0..15
            const int tl = m * 16 + rr;
            f32x4 v = *(const f32x4*)(stg + rr * STG + 4 * l15);
            const float iv = s_winv[tl];
            f32x4 p = *(const f32x4*)(peb + (size_t)tl * D_FIX);
            v[0] = v[0] * iv + p[0];
            v[1] = v[1] * iv + p[1];
            v[2] = v[2] * iv + p[2];
            v[3] = v[3] * iv + p[3];
            *(f32x4*)(ob + (size_t)tl * D_FIX) = v;
        }
    }
}

// ---------------- fallback (round-1 f32 kernel, used if ws too small) ----------------
#define FBM 32
#define BLOCK 256
__global__ __launch_bounds__(BLOCK) void gauss_up_f32(
    const float* __restrict__ enc, const float* __restrict__ dur,
    const float* __restrict__ rng, float* __restrict__ out,
    int T, int D, int ntiles)
{
    __shared__ float s_w[FBM][S_FIX];
    __shared__ float s_c[S_FIX];
    __shared__ float s_ir2[S_FIX];
    __shared__ float s_scan[S_FIX];
    __shared__ float s_part[8][FBM];
    __shared__ float s_winv[FBM];

    const int tid = threadIdx.x;
    const int b   = blockIdx.x / ntiles;
    const int t0  = (blockIdx.x % ntiles) * FBM;

    float dv = dur[b * S_FIX + tid];
    s_scan[tid] = dv;
    __syncthreads();
    #pragma unroll
    for (int off = 1; off < S_FIX; off <<= 1) {
        float cur = s_scan[tid];
        float add = (tid >= off) ? s_scan[tid - off] : 0.0f;
        __syncthreads();
        s_scan[tid] = cur + add;
        __syncthreads();
    }
    {
        float e = s_scan[tid];
        float c = e - 0.5f * dv;
        float r = rng[b * S_FIX + tid];
        s_c[tid] = c; s_ir2[tid] = 1.0f / (r * r);
    }
    __syncthreads();
    {
        float cc = s_c[tid], ir = s_ir2[tid];
        #pragma unroll 4
        for (int tl = 0; tl < FBM; ++tl) {
            float tt = (float)(t0 + tl);
            float df = tt - cc;
            s_w[tl][tid] = __expf(-ir * df * df);
        }
    }
    __syncthreads();
    {
        const int t = tid & 31, ch = tid >> 5;
        float ps = 0.0f;
        #pragma unroll 8
        for (int j = 0; j < 32; ++j) ps += s_w[t][ch * 32 + ((j + t) & 31)];
        s_part[ch][t] = ps;
    }
    __syncthreads();
    if (tid < FBM) {
        float w2 = s_part[0][tid] + s_part[1][tid] + s_part[2][tid] + s_part[3][tid]
                 + s_part[4][tid] + s_part[5][tid] + s_part[6][tid] + s_part[7][tid] + 1e-20f;
        s_winv[tid] = 1.0f / w2;
    }
    __syncthreads();

    const int dq = tid & 63, tg = tid >> 6;
    float4 acc[8];
    #pragma unroll
    for (int i = 0; i < 8; ++i) acc[i] = make_float4(0.f, 0.f, 0.f, 0.f);
    const float* encb = enc + (size_t)b * S_FIX * D + (size_t)dq * 4;
    #pragma unroll 4
    for (int s = 0; s < S_FIX; ++s) {
        float4 ev = *(const float4*)(encb + (size_t)s * D);
        #pragma unroll
        for (int i = 0; i < 8; ++i) {
            float wv = s_w[tg * 8 + i][s];
            acc[i].x = fmaf(wv, ev.x, acc[i].x);
            acc[i].y = fmaf(wv, ev.y, acc[i].y);
            acc[i].z = fmaf(wv, ev.z, acc[i].z);
            acc[i].w = fmaf(wv, ev.w, acc[i].w);
        }
    }
    const float kf = -logf(10000.0f) / (float)D;
    const int d0 = dq * 4;
    const float f0 = __expf(kf * (float)(d0));
    const float f2 = __expf(kf * (float)(d0 + 2));
    float* outb = out + (size_t)b * T * D + (size_t)t0 * D + d0;
    #pragma unroll
    for (int i = 0; i < 8; ++i) {
        const int tl = tg * 8 + i;
        const float inv = s_winv[tl];
        const float tt = (float)(t0 + tl);
        const float a0 = tt * f0, a2 = tt * f2;
        float4 o;
        o.x = acc[i].x * inv + __sinf(a0);
        o.y = acc[i].y * inv + __cosf(a0);
        o.z = acc[i].z * inv + __sinf(a2);
        o.w = acc[i].w * inv + __cosf(a2);
        *(float4*)(outb + (size_t)tl * D) = o;
    }
}

extern "C" void kernel_launch(void* const* d_in, const int* in_sizes, int n_in,
                              void* d_out, int out_size, void* d_ws, size_t ws_size,
                              hipStream_t stream) {
    const float* enc = (const float*)d_in[0];
    const float* dur = (const float*)d_in[1];
    const float* rng = (const float*)d_in[2];
    float* out = (float*)d_out;

    const int S  = S_FIX;
    const int BS = in_sizes[1];
    const int B  = BS / S;
    const int D  = in_sizes[0] / BS;
    const int T  = out_size / (B * D);

    const size_t need_encT = (size_t)B * D * S * sizeof(unsigned short);  // 4 MB
    const size_t need_pe   = (size_t)T * D * sizeof(float);               // 2 MB

    if (D == D_FIX && (T % BM) == 0 && ws_size >= need_encT + need_pe) {
        unsigned short* encT = (unsigned short*)d_ws;
        float* pe = (float*)((char*)d_ws + need_encT);
        const int nthr = B * (S / 8) * D;
        hipLaunchKernelGGL(transpose_enc_bf16, dim3(nthr / 256), dim3(256), 0, stream,
                           enc, encT);
        hipLaunchKernelGGL(pe_table, dim3(T * 64 / 256), dim3(256), 0, stream, pe);
        hipLaunchKernelGGL(gauss_up_mfma, dim3(B * (T / BM)), dim3(256), 0, stream,
                           dur, rng, encT, pe, out, T);
    } else {
        const int ntiles = T / FBM;
        hipLaunchKernelGGL(gauss_up_f32, dim3(B * ntiles), dim3(BLOCK), 0, stream,
                           enc, dur, rng, out, T, D, ntiles);
    }
}